// Round 10
// baseline (398.821 us; speedup 1.0000x reference)
//
#include <hip/hip_runtime.h>
#include <hip/hip_cooperative_groups.h>
#include <math.h>

namespace cg = cooperative_groups;

#define NW 14
#define NSTATE 16384
#define HALF 8192
#define QHALF 4096
#define NL 4
#define BATCH 128
#define TPB 1024
#define SHBYTES (2 * HALF * (int)sizeof(float2))   // psiA + psiB = 128 KB

// ---------------------------------------------------------------------------
// Wire w <-> index bit (13-w). Ring composite R (verified r1); scatter uses
// Rinv: Rinv(e_j)=((2<<j)-1)|e13 (j<=11), Rinv(e12)=0x3FFF, Rinv(e13)=0x1FFF.
// Block gid = q<<7|b owns half bit13=q.
//
// r10: single cooperative kernel. State lives in LDS (psiA/psiB, 128 KB).
// Boundary: slot s of the next state is remote-sourced iff bit0(s)=1
// (bit13 of Rinv = parity(bits0..12), s0 = s13^q_src). Exit routes the
// wire-1-gated pair (A0 at d0=sxmap(jc)^(q?0x1FFF:0), A1 at d0^0x3FFF):
// exactly one is local (even slot -> psiB), one remote (odd slot ->
// partner inbox, compacted >>1, agent-scope atomic store). grid.sync(),
// then merge applies the deferred wire-0 gate on pairs (se, se^0x1FFF)
// with row rc = q (r8-verified formula). Layer-0 = product state
// synthesized directly at J=R(I) (r9-verified). Final reduction fused.
// Register budget: loops keep <= ~8 float2 live (64-VGPR cap, r3-r5).
// ---------------------------------------------------------------------------

__device__ __forceinline__ unsigned sxmap(unsigned v) {   // v: bits 0..11
    unsigned t = v;
    t ^= t >> 1; t ^= t >> 2; t ^= t >> 4; t ^= t >> 8;
    return (t & 0x0FFFu) | ((t & 1u) << 13);              // = Rinv(v)
}

__device__ __forceinline__ float2 cmul(float2 u, float2 v) {
    return make_float2(u.x * v.x - u.y * v.y, u.x * v.y + u.y * v.x);
}

__device__ __forceinline__ void ag_store(float2* p, float2 v) {
    __hip_atomic_store(reinterpret_cast<unsigned long long*>(p),
                       __builtin_bit_cast(unsigned long long, v),
                       __ATOMIC_RELAXED, __HIP_MEMORY_SCOPE_AGENT);
}
__device__ __forceinline__ float2 ag_load(const float2* p) {
    unsigned long long u = __hip_atomic_load(
        reinterpret_cast<const unsigned long long*>(p),
        __ATOMIC_RELAXED, __HIP_MEMORY_SCOPE_AGENT);
    return __builtin_bit_cast(float2, u);
}

// Fused 1q gate G = RZ(t2)*RX(t1) (layer 0 folds data RX; verified r1-r9).
__device__ __forceinline__ float4 fused_coef(const float* weights,
                                             const float* states,
                                             int b, int l, int w) {
    float t1 = weights[(l * NW + w) * 2 + 0];
    float t2 = weights[(l * NW + w) * 2 + 1];
    if (l == 0) t1 += fabsf(states[(size_t)b * NSTATE + w]);
    float s, c, sz, cz;
    sincosf(0.5f * t1, &s, &c);
    sincosf(0.5f * t2, &sz, &cz);
    return make_float4(c * cz, -c * sz, -s * sz, -s * cz);
}

// SU(2) gate on register pairs (k,k|M); s3&M -> X-conjugated (verified r3-r9).
template<int N, int M>
__device__ __forceinline__ void gateN(float2* r, float4 g, unsigned s3) {
    const float f = (s3 & (unsigned)M) ? -1.0f : 1.0f;
    g.y *= f;
    g.z *= f;
#pragma unroll
    for (int k = 0; k < N; ++k) {
        if ((k & M) == 0) {
            const float x0 = r[k].x,   y0 = r[k].y;
            const float x1 = r[k|M].x, y1 = r[k|M].y;
            r[k].x   =  g.x*x0 - g.y*y0 + g.z*x1 - g.w*y1;
            r[k].y   =  g.x*y0 + g.y*x0 + g.z*y1 + g.w*x1;
            r[k|M].x = -g.z*x0 - g.w*y0 + g.x*x1 + g.y*y1;
            r[k|M].y = -g.z*y0 + g.w*x0 + g.x*y1 - g.y*x1;
        }
    }
}

// 3-bit in-LDS pass over the 13-bit half-state (verified r7-r9 swizzles).
template<int J0, int S3SH, int S3MSK>
__device__ __forceinline__ void pass3(float2* psi, const float4* gc,
                                      unsigned t) {
    const float4 gA = gc[13 - (J0 + 0)];
    const float4 gB = gc[13 - (J0 + 1)];
    const float4 gC = gc[13 - (J0 + 2)];
    const unsigned s3   = (t >> S3SH) & (unsigned)S3MSK;
    const unsigned low  = t & ((1u << J0) - 1u);
    const unsigned high = (t >> J0) << (J0 + 3);
    float2 r[8];
#pragma unroll
    for (int k = 0; k < 8; ++k)
        r[k] = psi[low | (((unsigned)k ^ s3) << J0) | high];
    gateN<8,1>(r, gA, s3);
    gateN<8,2>(r, gB, s3);
    gateN<8,4>(r, gC, s3);
#pragma unroll
    for (int k = 0; k < 8; ++k)
        psi[low | (((unsigned)k ^ s3) << J0) | high] = r[k];
}

// Exit: wire-1 (bit12) gate + Rinv routing: local (even) slot -> psiB,
// remote (odd) slot -> partner inbox (compacted >>1).
__device__ __forceinline__ void exit_exchange(const float2* psiA,
                                              float2* psiB, float2* inboxP,
                                              float4 g1, unsigned q,
                                              unsigned tid) {
#pragma unroll
    for (int m = 0; m < 4; ++m) {
        const unsigned jc = tid + (unsigned)m * TPB;  // bits 0..11
        const float2 x0 = psiA[jc];
        const float2 x1 = psiA[jc | 0x1000u];
        float2 A0, A1;                                 // r8-verified g1 apply
        A0.x =  g1.x*x0.x - g1.y*x0.y + g1.z*x1.x - g1.w*x1.y;
        A0.y =  g1.x*x0.y + g1.y*x0.x + g1.z*x1.y + g1.w*x1.x;
        A1.x = -g1.z*x0.x - g1.w*x0.y + g1.x*x1.x + g1.y*x1.y;
        A1.y = -g1.z*x0.y + g1.w*x0.x + g1.x*x1.y - g1.y*x1.x;
        const unsigned d0 = sxmap(jc) ^ (q ? 0x1FFFu : 0u);
        const unsigned d1 = d0 ^ 0x3FFFu;              // bit13 flips
        const bool loc0 = (d0 >> 13) == q;
        const float2  La = loc0 ? A0 : A1;
        const unsigned Ls = (loc0 ? d0 : d1) & 0x1FFFu;      // even
        const float2  Ra = loc0 ? A1 : A0;
        const unsigned Rs = ((loc0 ? d1 : d0) & 0x1FFFu) >> 1;
        psiB[Ls] = La;
        ag_store(inboxP + Rs, Ra);
    }
}

// Merge: deferred wire-0 (bit13) gate on pairs (se even local, se^0x1FFF
// remote from inbox); row of local = q (r8-verified entry formula).
__device__ __forceinline__ void merge_entry(const float2* psiB,
                                            const float2* inbox,
                                            float2* psiA, float4 ge,
                                            unsigned q, unsigned tid) {
    const float aar = ge.x, aai = q ? -ge.y : ge.y;
    const float bbr = q ? -ge.z : ge.z, bbi = ge.w;
#pragma unroll
    for (int m = 0; m < 4; ++m) {
        const unsigned se = 2u * (tid + (unsigned)m * TPB);
        const unsigned so = se ^ 0x1FFFu;
        const float2 f0 = psiB[se];
        const float2 f1 = ag_load(inbox + (so >> 1));
        float2 oc, op;
        oc.x = aar*f0.x - aai*f0.y + bbr*f1.x - bbi*f1.y;
        oc.y = aar*f0.y + aai*f0.x + bbr*f1.y + bbi*f1.x;
        op.x = aar*f1.x + aai*f1.y - (bbr*f0.x + bbi*f0.y);
        op.y = aar*f1.y - aai*f1.x - (bbr*f0.y - bbi*f0.x);
        psiA[se] = oc;
        psiA[so] = op;
    }
}

__global__ __launch_bounds__(TPB) void qsim_coop(
    const float* __restrict__ states, const float* __restrict__ weights,
    const float* __restrict__ head_w, const float* __restrict__ head_b,
    float2* __restrict__ EX0, float2* __restrict__ EX1,
    float* __restrict__ out)
{
    extern __shared__ float2 dyn[];
    float2* psiA = dyn;            // 64 KB
    float2* psiB = dyn + HALF;     // 64 KB
    __shared__ float4 gc4[NL * NW];
    __shared__ float2 vfac[NW][2];
    __shared__ float2 T1[128];
    __shared__ float2 T2[128];
    __shared__ float wsum[TPB / 64];

    cg::grid_group grid = cg::this_grid();
    const unsigned gid = blockIdx.x, q = gid >> 7, b = gid & 127u;
    const unsigned tid = threadIdx.x;
    float2* inboxMine0 = EX0 + (size_t)gid * QHALF;
    float2* inboxPart0 = EX0 + (size_t)(gid ^ 128u) * QHALF;
    float2* inboxMine1 = EX1 + (size_t)gid * QHALF;
    float2* inboxPart1 = EX1 + (size_t)(gid ^ 128u) * QHALF;

    if (tid < NL * NW)
        gc4[tid] = fused_coef(weights, states, (int)b,
                              (int)tid / NW, (int)tid % NW);
    __syncthreads();
    if (tid < NW) {
        vfac[tid][0] = make_float2(gc4[tid].x, gc4[tid].y);    // G|0> bit=0
        vfac[tid][1] = make_float2(-gc4[tid].z, gc4[tid].w);   // G|0> bit=1
    }
    __syncthreads();
    if (tid < 128) {
        float2 p = make_float2(1.0f, 0.0f);
#pragma unroll
        for (int j = 0; j < 7; ++j)
            p = cmul(p, vfac[13 - j][(tid >> j) & 1u]);
        T1[tid] = p;
    } else if (tid < 256) {
        const unsigned u = tid - 128;
        float2 p = make_float2(1.0f, 0.0f);
#pragma unroll
        for (int j = 7; j < 14; ++j)
            p = cmul(p, vfac[13 - j][(u >> (j - 7)) & 1u]);
        T2[u] = p;
    }
    __syncthreads();

    // Layer-0 post-ring product state at J = R(q<<13 | I)  (r9-verified).
#pragma unroll
    for (int m = 0; m < 8; ++m) {
        const unsigned I  = tid + (unsigned)m * TPB;
        const unsigned If = I | (q << 13);
        const unsigned lo  = (If ^ (If >> 1)) & 0x0FFFu;
        const unsigned y12 = ((If >> 12) ^ (If >> 13) ^ If) & 1u;
        const unsigned y13 = ((If >> 13) ^ If) & 1u;
        const unsigned J = lo | (y12 << 12) | (y13 << 13);
        psiA[I] = cmul(T1[J & 127u], T2[J >> 7]);
    }
    __syncthreads();

    // ---- layer 1 ----
    pass3<0, 1, 7>(psiA, gc4 + 1 * NW, tid);  __syncthreads();
    pass3<3, 3, 1>(psiA, gc4 + 1 * NW, tid);  __syncthreads();
    pass3<6, 0, 0>(psiA, gc4 + 1 * NW, tid);  __syncthreads();
    pass3<9, 0, 0>(psiA, gc4 + 1 * NW, tid);  __syncthreads();
    exit_exchange(psiA, psiB, inboxPart0, gc4[1 * NW + 1], q, tid);
    __threadfence();
    grid.sync();
    merge_entry(psiB, inboxMine0, psiA, gc4[1 * NW + 0], q, tid);
    __syncthreads();

    // ---- layer 2 ----
    pass3<0, 1, 7>(psiA, gc4 + 2 * NW, tid);  __syncthreads();
    pass3<3, 3, 1>(psiA, gc4 + 2 * NW, tid);  __syncthreads();
    pass3<6, 0, 0>(psiA, gc4 + 2 * NW, tid);  __syncthreads();
    pass3<9, 0, 0>(psiA, gc4 + 2 * NW, tid);  __syncthreads();
    exit_exchange(psiA, psiB, inboxPart1, gc4[2 * NW + 1], q, tid);
    __threadfence();
    grid.sync();
    merge_entry(psiB, inboxMine1, psiA, gc4[2 * NW + 0], q, tid);
    __syncthreads();

    // ---- layer 3 ----
    pass3<0, 1, 7>(psiA, gc4 + 3 * NW, tid);  __syncthreads();
    pass3<3, 3, 1>(psiA, gc4 + 3 * NW, tid);  __syncthreads();
    pass3<6, 0, 0>(psiA, gc4 + 3 * NW, tid);  __syncthreads();
    pass3<9, 0, 0>(psiA, gc4 + 3 * NW, tid);  __syncthreads();
    exit_exchange(psiA, psiB, inboxPart0, gc4[3 * NW + 1], q, tid);
    __threadfence();
    grid.sync();

    // ---- final: deferred layer-3 wire-0 gate + <Z> contraction + head ----
    const float4 ge = gc4[3 * NW + 0];
    const float aar = ge.x, aai = q ? -ge.y : ge.y;
    const float bbr = q ? -ge.z : ge.z, bbi = ge.w;

    float hw[NW];
#pragma unroll
    for (int i = 0; i < NW; ++i) hw[i] = head_w[i];
    // se bit (p+1) = tid bit p -> wire 12-p; se bit 11,12 = m -> wires 2,1;
    // bit13 = q -> wire 0; se bit0 = 0 (wire 13).
    float cvt = 0.0f;
#pragma unroll
    for (int i = 0; i < NW; ++i) cvt += hw[i];
    if (q) cvt -= 2.0f * hw[0];
#pragma unroll
    for (int p = 0; p < 10; ++p)
        if ((tid >> p) & 1u) cvt -= 2.0f * hw[12 - p];
    const float s0w = 1.0f - 2.0f * (float)q;

    float acc = 0.0f;
#pragma unroll
    for (int m = 0; m < 4; ++m) {
        const unsigned se = 2u * (tid + (unsigned)m * TPB);
        const unsigned so = se ^ 0x1FFFu;
        const float2 f0 = psiB[se];
        const float2 f1 = ag_load(inboxMine0 + (so >> 1));
        float2 oc, op;
        oc.x = aar*f0.x - aai*f0.y + bbr*f1.x - bbi*f1.y;
        oc.y = aar*f0.y + aai*f0.x + bbr*f1.y + bbi*f1.x;
        op.x = aar*f1.x + aai*f1.y - (bbr*f0.x + bbi*f0.y);
        op.y = aar*f1.y - aai*f1.x - (bbr*f0.y - bbi*f0.x);
        float cv_c = cvt;
        if (m & 1) cv_c -= 2.0f * hw[2];
        if (m & 2) cv_c -= 2.0f * hw[1];
        const float cv_p = 2.0f * hw[0] * s0w - cv_c;  // partner flips w1..13
        acc += (oc.x*oc.x + oc.y*oc.y) * cv_c
             + (op.x*op.x + op.y*op.y) * cv_p;
    }
#pragma unroll
    for (int off = 32; off > 0; off >>= 1)
        acc += __shfl_down(acc, off, 64);
    if ((tid & 63u) == 0) wsum[tid >> 6] = acc;
    __syncthreads();
    if (tid == 0) {
        float tot = 0.0f;
#pragma unroll
        for (int i = 0; i < TPB / 64; ++i) tot += wsum[i];
        if (q == 0) tot += head_b[0];
        atomicAdd(out + b, tot);
    }
}

extern "C" void kernel_launch(void* const* d_in, const int* in_sizes, int n_in,
                              void* d_out, int out_size, void* d_ws, size_t ws_size,
                              hipStream_t stream) {
    const float* states  = (const float*)d_in[0];  // (128, 16384)
    const float* weights = (const float*)d_in[1];  // (4, 14, 2)
    const float* head_w  = (const float*)d_in[2];  // (1, 14)
    const float* head_b  = (const float*)d_in[3];  // (1,)
    float* out = (float*)d_out;                    // (128,)

    float2* EX0 = (float2*)d_ws;                   // 256*4096 float2 = 8 MB
    float2* EX1 = EX0 + (size_t)256 * QHALF;       // 8 MB

    hipMemsetAsync(out, 0, BATCH * sizeof(float), stream);
    void* args[] = {(void*)&states, (void*)&weights, (void*)&head_w,
                    (void*)&head_b, (void*)&EX0, (void*)&EX1, (void*)&out};
    hipLaunchCooperativeKernel((const void*)qsim_coop, dim3(2 * BATCH),
                               dim3(TPB), args, (unsigned)SHBYTES, stream);
}

// Round 11
// 102.517 us; speedup vs baseline: 3.8903x; 3.8903x over previous
//
#include <hip/hip_runtime.h>
#include <math.h>

#define NW 14
#define NSTATE 16384
#define HALF 8192
#define NL 4
#define BATCH 128
#define TPB 1024
#define SHB1 (84 * 1024)                              // k_layer1: force 1 blk/CU
#define SHB2 ((NSTATE + 3 * TPB) * (int)sizeof(float2))  // k_rest: 128+24 KB

// ---------------------------------------------------------------------------
// Wire w <-> index bit (13-w). Ring composite R (verified r1):
//   y_p = x_p^x_{p+1} (p<=11), y12 = x12^x13^x0, y13 = x13^x0.
// Rinv basis (verified): Rinv(e_j)=((2<<j)-1)|e13 (j<=11), Rinv(e12)=0x3FFF,
//   Rinv(e13)=0x1FFF; Rinv(e10)=0x27FF, Rinv(e11)=0x2FFF.
//
// r11 = r9 structure minus 2 dispatches (r10 coop was a 3x regression —
// grid.sync + cross-XCD inboxes latency-bound at 138 GB/s):
//   D1 k_layer1 (r9 verbatim, 256 blocks, half-state): layer-0 product
//      synth + layer-1 local wires + wire-1 + Rinv relabel scatter -> SA
//      (wire-0 of layer 1 deferred).
//   D2 k_rest (128 blocks, FULL state in 128 KB LDS + 24 KB spare =
//      r6/r7-verified layout): entry = r9-k_final's verified pair read
//      (applies deferred layer-1 wire-0) -> LDS; layer 2 = 4x pass3f +
//      passE (r7 verbatim: wires 1,0 + in-LDS ring perm); layer 3 =
//      4x pass3f + wires 1,0 in registers + contraction with the FINAL
//      ring perm folded into the <Z> masks:
//        sum_I |post[I]|^2 cv(I) = sum_J |pre[J]|^2 cv(Rinv(J)),
//        bit_p(Rinv(J)) = XOR(J_p..J_13) for p<=12,
//        bit_13(Rinv(J)) = XOR(J_0..J_12).
//      Direct out[b] write (no memset/atomics).
// Register budget: 64-VGPR cap (r3-r5 immovable) — all loops <= ~13 float2.
// ---------------------------------------------------------------------------

#define B4_  0x201Fu
#define B5_  0x203Fu
#define B12_ 0x3FFFu
#define B13_ 0x1FFFu

__device__ __forceinline__ unsigned sxmap(unsigned v) {   // v: bits 0..11
    unsigned t = v;
    t ^= t >> 1; t ^= t >> 2; t ^= t >> 4; t ^= t >> 8;
    return (t & 0x0FFFu) | ((t & 1u) << 13);              // = Rinv(v)
}

__device__ __forceinline__ float2 cmul(float2 u, float2 v) {
    return make_float2(u.x * v.x - u.y * v.y, u.x * v.y + u.y * v.x);
}

// Fused 1q gate G = RZ(t2)*RX(t1) (layer 0 folds data RX; verified r1-r9).
__device__ __forceinline__ float4 fused_coef(const float* weights,
                                             const float* states,
                                             int b, int l, int w) {
    float t1 = weights[(l * NW + w) * 2 + 0];
    float t2 = weights[(l * NW + w) * 2 + 1];
    if (l == 0) t1 += fabsf(states[(size_t)b * NSTATE + w]);
    float s, c, sz, cz;
    sincosf(0.5f * t1, &s, &c);
    sincosf(0.5f * t2, &sz, &cz);
    return make_float4(c * cz, -c * sz, -s * sz, -s * cz);
}

// SU(2) gate on register pairs (k,k|M); s3&M -> X-conjugated (verified r3-r9).
template<int N, int M>
__device__ __forceinline__ void gateN(float2* r, float4 g, unsigned s3) {
    const float f = (s3 & (unsigned)M) ? -1.0f : 1.0f;
    g.y *= f;
    g.z *= f;
#pragma unroll
    for (int k = 0; k < N; ++k) {
        if ((k & M) == 0) {
            const float x0 = r[k].x,   y0 = r[k].y;
            const float x1 = r[k|M].x, y1 = r[k|M].y;
            r[k].x   =  g.x*x0 - g.y*y0 + g.z*x1 - g.w*y1;
            r[k].y   =  g.x*y0 + g.y*x0 + g.z*y1 + g.w*x1;
            r[k|M].x = -g.z*x0 - g.w*y0 + g.x*x1 + g.y*y1;
            r[k|M].y = -g.z*y0 + g.w*x0 + g.x*y1 - g.y*x1;
        }
    }
}

// 3-bit pass over the 13-bit HALF-state (r9 verbatim).
template<int J0, int S3SH, int S3MSK>
__device__ __forceinline__ void pass3h(float2* psi, const float4* gc,
                                       unsigned t) {
    const float4 gA = gc[13 - (J0 + 0)];
    const float4 gB = gc[13 - (J0 + 1)];
    const float4 gC = gc[13 - (J0 + 2)];
    const unsigned s3   = (t >> S3SH) & (unsigned)S3MSK;
    const unsigned low  = t & ((1u << J0) - 1u);
    const unsigned high = (t >> J0) << (J0 + 3);
    float2 r[8];
#pragma unroll
    for (int k = 0; k < 8; ++k)
        r[k] = psi[low | (((unsigned)k ^ s3) << J0) | high];
    gateN<8,1>(r, gA, s3);
    gateN<8,2>(r, gB, s3);
    gateN<8,4>(r, gC, s3);
#pragma unroll
    for (int k = 0; k < 8; ++k)
        psi[low | (((unsigned)k ^ s3) << J0) | high] = r[k];
}

// 3-bit pass over the 14-bit FULL state (r7 verbatim; two r[8] iterations).
template<int J0, int S3SH, int S3MSK>
__device__ __forceinline__ void pass3f(float2* psi, const float4* gc,
                                       unsigned t) {
    const float4 gA = gc[13 - (J0 + 0)];
    const float4 gB = gc[13 - (J0 + 1)];
    const float4 gC = gc[13 - (J0 + 2)];
    const unsigned s3 = (t >> S3SH) & (unsigned)S3MSK;
#pragma unroll
    for (int m = 0; m < 2; ++m) {
        const unsigned x    = t | ((unsigned)m << 10);   // 11 non-group bits
        const unsigned low  = x & ((1u << J0) - 1u);
        const unsigned high = (x >> J0) << (J0 + 3);
        float2 r[8];
#pragma unroll
        for (int k = 0; k < 8; ++k)
            r[k] = psi[low | (((unsigned)k ^ s3) << J0) | high];
        gateN<8,1>(r, gA, s3);
        gateN<8,2>(r, gB, s3);
        gateN<8,4>(r, gC, s3);
#pragma unroll
        for (int k = 0; k < 8; ++k)
            psi[low | (((unsigned)k ^ s3) << J0) | high] = r[k];
    }
}

// Full-state wires 1,0 + ring perm, cell 0 parked in spare LDS (r7 verbatim).
__device__ __forceinline__ void passE(float2* psi, float2* spare,
                                      const float4* gc4, int l, unsigned t) {
    const float4 g1 = gc4[l*NW + 1];   // index bit 12 -> wire 1
    const float4 g0 = gc4[l*NW + 0];   // index bit 13 -> wire 0

    unsigned v = t;
    v ^= v >> 1; v ^= v >> 2; v ^= v >> 4; v ^= v >> 8;
    const unsigned Rinv0 = (v & 0x0FFFu) | ((v & 1u) << 13);

    float2 c0[4];
#pragma unroll
    for (int k = 0; k < 4; ++k) c0[k] = psi[t | ((unsigned)k << 12)];
    gateN<4,1>(c0, g1, 0u);
    gateN<4,2>(c0, g0, 0u);
    spare[3*t+0] = c0[1];
    spare[3*t+1] = c0[2];
    spare[3*t+2] = c0[3];
    const float2 keep = c0[0];

    float2 r[12];
#pragma unroll
    for (int m = 1; m < 4; ++m) {
        const unsigned base = t | ((unsigned)m << 10);
#pragma unroll
        for (int k = 0; k < 4; ++k)
            r[(m-1)*4 + k] = psi[base | ((unsigned)k << 12)];
    }
#pragma unroll
    for (int m = 0; m < 3; ++m) {
        gateN<4,1>(r + 4*m, g1, 0u);
        gateN<4,2>(r + 4*m, g0, 0u);
    }

    __syncthreads();   // all psi gathers done -> in-place scatter is safe

#pragma unroll
    for (int m = 1; m < 4; ++m) {
        const unsigned Rb = Rinv0 ^ ((m & 1) ? 0x27FFu : 0u)
                                  ^ ((m & 2) ? 0x2FFFu : 0u);
#pragma unroll
        for (int k = 0; k < 4; ++k) {
            const unsigned CK = ((k & 1) ? B12_ : 0u) ^ ((k & 2) ? B13_ : 0u);
            psi[Rb ^ CK] = r[(m-1)*4 + k];
        }
    }
    psi[Rinv0]           = keep;
    psi[Rinv0 ^ B12_]    = spare[3*t+0];
    psi[Rinv0 ^ B13_]    = spare[3*t+1];
    psi[Rinv0 ^ 0x2000u] = spare[3*t+2];
}

// Half-state exit: wire-1 (bit12) gate + Rinv-relabel scatter (r9 verbatim).
__device__ __forceinline__ void exit_scatter(const float2* psi,
                                             float2* __restrict__ dst,
                                             float4 g1, unsigned q,
                                             unsigned tid) {
#pragma unroll
    for (int m = 0; m < 4; ++m) {
        const unsigned jc = tid + (unsigned)m * TPB;  // bits 0..11
        const float2 x0 = psi[jc];
        const float2 x1 = psi[jc | 0x1000u];
        float2 A0, A1;
        A0.x =  g1.x*x0.x - g1.y*x0.y + g1.z*x1.x - g1.w*x1.y;
        A0.y =  g1.x*x0.y + g1.y*x0.x + g1.z*x1.y + g1.w*x1.x;
        A1.x = -g1.z*x0.x - g1.w*x0.y + g1.x*x1.x + g1.y*x1.y;
        A1.y = -g1.z*x0.y + g1.w*x0.x + g1.x*x1.y - g1.y*x1.x;
        const unsigned d0 = sxmap(jc) ^ (q ? 0x1FFFu : 0u);
        dst[d0]           = A0;
        dst[d0 ^ 0x3FFFu] = A1;   // ^Rinv(e12)
    }
}

// D1 (r9 verbatim): layer-0 product synth + layer-1 + exit -> SA.
__global__ __launch_bounds__(TPB) void k_layer1(
    const float* __restrict__ states, const float* __restrict__ weights,
    float2* __restrict__ Sout)
{
    extern __shared__ float2 psi[];   // HALF float2 = 64 KB (84 KB requested)
    __shared__ float2 vfac[NW][2];
    __shared__ float2 T1[128];
    __shared__ float2 T2[128];
    __shared__ float4 gc[NW];
    const unsigned gid = blockIdx.x, q = gid >> 7, b = gid & 127u;
    const unsigned tid = threadIdx.x;

    if (tid < NW) {
        float4 g = fused_coef(weights, states, (int)b, 0, (int)tid);
        vfac[tid][0] = make_float2(g.x, g.y);
        vfac[tid][1] = make_float2(-g.z, g.w);
    }
    if (tid >= 64 && tid < 64 + NW)
        gc[tid - 64] = fused_coef(weights, states, (int)b, 1, (int)(tid - 64));
    __syncthreads();
    if (tid < 128) {
        float2 p = make_float2(1.0f, 0.0f);
#pragma unroll
        for (int j = 0; j < 7; ++j)
            p = cmul(p, vfac[13 - j][(tid >> j) & 1u]);
        T1[tid] = p;
    } else if (tid < 256) {
        const unsigned u = tid - 128;
        float2 p = make_float2(1.0f, 0.0f);
#pragma unroll
        for (int j = 7; j < 14; ++j)
            p = cmul(p, vfac[13 - j][(u >> (j - 7)) & 1u]);
        T2[u] = p;
    }
    __syncthreads();

#pragma unroll
    for (int m = 0; m < 8; ++m) {
        const unsigned I  = tid + (unsigned)m * TPB;
        const unsigned If = I | (q << 13);
        const unsigned lo  = (If ^ (If >> 1)) & 0x0FFFu;
        const unsigned y12 = ((If >> 12) ^ (If >> 13) ^ If) & 1u;
        const unsigned y13 = ((If >> 13) ^ If) & 1u;
        const unsigned J = lo | (y12 << 12) | (y13 << 13);
        psi[I] = cmul(T1[J & 127u], T2[J >> 7]);
    }
    __syncthreads();

    pass3h<0, 1, 7>(psi, gc, tid);  __syncthreads();
    pass3h<3, 3, 1>(psi, gc, tid);  __syncthreads();
    pass3h<6, 0, 0>(psi, gc, tid);  __syncthreads();
    pass3h<9, 0, 0>(psi, gc, tid);  __syncthreads();

    exit_scatter(psi, Sout + (size_t)b * NSTATE, gc[1], q, tid);
}

// D2: full-state (one block per sample): deferred layer-1 wire-0 entry;
// layer 2 fully local (incl. ring perm); layer 3 local wires + final ring
// perm folded into the contraction masks; direct out[b] write.
__global__ __launch_bounds__(TPB) void k_rest(
    const float* __restrict__ states, const float* __restrict__ weights,
    const float* __restrict__ head_w, const float* __restrict__ head_b,
    const float2* __restrict__ Sin, float* __restrict__ out)
{
    extern __shared__ float2 dyn[];
    float2* psi   = dyn;            // 16384 float2 = 128 KB
    float2* spare = dyn + NSTATE;   //  3072 float2 =  24 KB
    __shared__ float4 gc4[NL * NW];
    __shared__ float wsum[TPB / 64];
    const unsigned b = blockIdx.x;
    const unsigned tid = threadIdx.x;

    if (tid < NL * NW)
        gc4[tid] = fused_coef(weights, states, (int)b,
                              (int)tid / NW, (int)tid % NW);
    __syncthreads();

    // Entry: r9-k_final's verified pair read (deferred layer-1 wire-0 gate),
    // writing the merged state into LDS at full labels.
    {
        const float4 ge = gc4[1 * NW + 0];
#pragma unroll
        for (int qm = 0; qm < 8; ++qm) {
            const unsigned q = (unsigned)qm >> 2;
            const unsigned m = (unsigned)qm & 3u;
            const float2* src = Sin + (size_t)b * NSTATE + (size_t)q * HALF;
            const unsigned ic = tid + m * TPB;            // bit12 = 0
            const float2 f0 = src[ic];
            const float2 f1 = src[ic ^ 0x1FFFu];
            const unsigned rc = (q ^ ic) & 1u;
            const float aar = ge.x, aai = rc ? -ge.y : ge.y;
            const float bbr = rc ? -ge.z : ge.z, bbi = ge.w;
            float2 oc, op;
            oc.x = aar*f0.x - aai*f0.y + bbr*f1.x - bbi*f1.y;
            oc.y = aar*f0.y + aai*f0.x + bbr*f1.y + bbi*f1.x;
            op.x = aar*f1.x + aai*f1.y - (bbr*f0.x + bbi*f0.y);
            op.y = aar*f1.y - aai*f1.x - (bbr*f0.y - bbi*f0.x);
            psi[(q << 13) | ic]            = oc;
            psi[(q << 13) | (ic ^ 0x1FFFu)] = op;
        }
    }
    __syncthreads();

    // ---- layer 2: fully local ----
    pass3f<0, 1, 7>(psi, gc4 + 2 * NW, tid);  __syncthreads();
    pass3f<3, 3, 1>(psi, gc4 + 2 * NW, tid);  __syncthreads();
    pass3f<6, 0, 0>(psi, gc4 + 2 * NW, tid);  __syncthreads();
    pass3f<9, 0, 0>(psi, gc4 + 2 * NW, tid);  __syncthreads();
    passE(psi, spare, gc4, 2, tid);           __syncthreads();

    // ---- layer 3: local wires 13..2 ----
    pass3f<0, 1, 7>(psi, gc4 + 3 * NW, tid);  __syncthreads();
    pass3f<3, 3, 1>(psi, gc4 + 3 * NW, tid);  __syncthreads();
    pass3f<6, 0, 0>(psi, gc4 + 3 * NW, tid);  __syncthreads();
    pass3f<9, 0, 0>(psi, gc4 + 3 * NW, tid);  __syncthreads();

    // ---- layer-3 wires 1,0 + contraction with cv(Rinv(J)) ----
    float hw[NW];
#pragma unroll
    for (int i = 0; i < NW; ++i) hw[i] = head_w[i];
    float H = 0.0f, H12 = 0.0f;
#pragma unroll
    for (int i = 0; i < NW; ++i) H += hw[i];
#pragma unroll
    for (int i = 2; i < NW; ++i) H12 += hw[i];

    const float4 g1 = gc4[3 * NW + 1];   // wire 1 (bit12)
    const float4 g0 = gc4[3 * NW + 0];   // wire 0 (bit13)

    float acc = 0.0f;
#pragma unroll
    for (int m2 = 0; m2 < 4; ++m2) {
        const unsigned base = tid | ((unsigned)m2 << 10);  // bits 0..11
        float2 r[4];
#pragma unroll
        for (int k = 0; k < 4; ++k)
            r[k] = psi[base | ((unsigned)k << 12)];
        gateN<4,1>(r, g1, 0u);
        gateN<4,2>(r, g0, 0u);
        // A = sum_{p<=11} hw[13-p]*suffix_xor(base, p..11); P = parity(base)
        float A = 0.0f;
        unsigned sfx = 0u;
#pragma unroll
        for (int p = 11; p >= 0; --p) {
            sfx ^= (base >> p) & 1u;
            if (sfx) A += hw[13 - p];
        }
        const unsigned P = sfx;
#pragma unroll
        for (int k = 0; k < 4; ++k) {
            const unsigned u   = ((unsigned)k ^ ((unsigned)k >> 1)) & 1u; // J12^J13
            const unsigned b13 = P ^ ((unsigned)k & 1u);                  // parity J0..J12
            float sum = u ? (H12 - A) : A;
            if (u)   sum += hw[1];
            if (b13) sum += hw[0];
            const float cv = H - 2.0f * sum;
            acc += (r[k].x * r[k].x + r[k].y * r[k].y) * cv;
        }
    }
#pragma unroll
    for (int off = 32; off > 0; off >>= 1)
        acc += __shfl_down(acc, off, 64);
    if ((tid & 63u) == 0) wsum[tid >> 6] = acc;
    __syncthreads();
    if (tid == 0) {
        float tot = 0.0f;
#pragma unroll
        for (int i = 0; i < TPB / 64; ++i) tot += wsum[i];
        out[b] = tot + head_b[0];
    }
}

extern "C" void kernel_launch(void* const* d_in, const int* in_sizes, int n_in,
                              void* d_out, int out_size, void* d_ws, size_t ws_size,
                              hipStream_t stream) {
    const float* states  = (const float*)d_in[0];  // (128, 16384)
    const float* weights = (const float*)d_in[1];  // (4, 14, 2)
    const float* head_w  = (const float*)d_in[2];  // (1, 14)
    const float* head_b  = (const float*)d_in[3];  // (1,)
    float* out = (float*)d_out;                    // (128,)

    float2* SA = (float2*)d_ws;                    // 16 MB

    k_layer1<<<2 * BATCH, TPB, SHB1, stream>>>(states, weights, SA);
    k_rest  <<<BATCH, TPB, SHB2, stream>>>(states, weights, head_w, head_b,
                                           SA, out);
}

// Round 12
// 101.117 us; speedup vs baseline: 3.9442x; 1.0138x over previous
//
#include <hip/hip_runtime.h>
#include <math.h>

#define NW 14
#define NSTATE 16384
#define HALF 8192
#define NL 4
#define BATCH 128
#define TPB 1024
#define SHB1 (84 * 1024)                              // k_layer1: force 1 blk/CU
#define SHB2 ((NSTATE + 3 * TPB) * (int)sizeof(float2))  // k_rest: 128+24 KB

// ---------------------------------------------------------------------------
// Wire w <-> index bit (13-w). Ring composite R (verified r1):
//   y_p = x_p^x_{p+1} (p<=11), y12 = x12^x13^x0, y13 = x13^x0.
// Rinv basis (verified): Rinv(e_j)=((2<<j)-1)|e13 (j<=11), Rinv(e12)=0x3FFF,
//   Rinv(e13)=0x1FFF; Rinv(e10)=0x27FF, Rinv(e11)=0x2FFF.
//
// r12 = r11 (verified, 102.5us) with BARRIER ELISION between wave-local
// passes. Dataflow (verified by slot->writer-thread algebra, both pass3f
// and pass3h): pass<0>->pass<3> exchanges only among threads differing in
// tid bits 0-2; pass<3>->pass<6> bits 3-5 -> SAME 64-lane wave. A wave's
// ds_writes precede its ds_reads in program order (single instruction
// stream; compiler emits lgkmcnt waits for the aliasing LDS pointer), so
// no __syncthreads needed there. pass<6>->pass<9> exchanges tid bits 6-8
// (wave index) -> barrier kept. Entry/passE/exit transitions cross waves
// -> barriers kept. k_rest: 10 -> 6 barriers; k_layer1: 4 -> 2.
// Register budget: 64-VGPR cap (r3-r5 immovable) — loops <= ~13 float2.
// ---------------------------------------------------------------------------

#define B4_  0x201Fu
#define B5_  0x203Fu
#define B12_ 0x3FFFu
#define B13_ 0x1FFFu

// Compile-time scheduling fence only (no runtime cost): keeps the compiler
// from migrating LDS ops across the wave-local pass boundary.
#define WAVE_FENCE() __builtin_amdgcn_wave_barrier()

__device__ __forceinline__ unsigned sxmap(unsigned v) {   // v: bits 0..11
    unsigned t = v;
    t ^= t >> 1; t ^= t >> 2; t ^= t >> 4; t ^= t >> 8;
    return (t & 0x0FFFu) | ((t & 1u) << 13);              // = Rinv(v)
}

__device__ __forceinline__ float2 cmul(float2 u, float2 v) {
    return make_float2(u.x * v.x - u.y * v.y, u.x * v.y + u.y * v.x);
}

// Fused 1q gate G = RZ(t2)*RX(t1) (layer 0 folds data RX; verified r1-r11).
__device__ __forceinline__ float4 fused_coef(const float* weights,
                                             const float* states,
                                             int b, int l, int w) {
    float t1 = weights[(l * NW + w) * 2 + 0];
    float t2 = weights[(l * NW + w) * 2 + 1];
    if (l == 0) t1 += fabsf(states[(size_t)b * NSTATE + w]);
    float s, c, sz, cz;
    sincosf(0.5f * t1, &s, &c);
    sincosf(0.5f * t2, &sz, &cz);
    return make_float4(c * cz, -c * sz, -s * sz, -s * cz);
}

// SU(2) gate on register pairs (k,k|M); s3&M -> X-conjugated (verified r3+).
template<int N, int M>
__device__ __forceinline__ void gateN(float2* r, float4 g, unsigned s3) {
    const float f = (s3 & (unsigned)M) ? -1.0f : 1.0f;
    g.y *= f;
    g.z *= f;
#pragma unroll
    for (int k = 0; k < N; ++k) {
        if ((k & M) == 0) {
            const float x0 = r[k].x,   y0 = r[k].y;
            const float x1 = r[k|M].x, y1 = r[k|M].y;
            r[k].x   =  g.x*x0 - g.y*y0 + g.z*x1 - g.w*y1;
            r[k].y   =  g.x*y0 + g.y*x0 + g.z*y1 + g.w*x1;
            r[k|M].x = -g.z*x0 - g.w*y0 + g.x*x1 + g.y*y1;
            r[k|M].y = -g.z*y0 + g.w*x0 + g.x*y1 - g.y*x1;
        }
    }
}

// 3-bit pass over the 13-bit HALF-state (r9 verbatim).
template<int J0, int S3SH, int S3MSK>
__device__ __forceinline__ void pass3h(float2* psi, const float4* gc,
                                       unsigned t) {
    const float4 gA = gc[13 - (J0 + 0)];
    const float4 gB = gc[13 - (J0 + 1)];
    const float4 gC = gc[13 - (J0 + 2)];
    const unsigned s3   = (t >> S3SH) & (unsigned)S3MSK;
    const unsigned low  = t & ((1u << J0) - 1u);
    const unsigned high = (t >> J0) << (J0 + 3);
    float2 r[8];
#pragma unroll
    for (int k = 0; k < 8; ++k)
        r[k] = psi[low | (((unsigned)k ^ s3) << J0) | high];
    gateN<8,1>(r, gA, s3);
    gateN<8,2>(r, gB, s3);
    gateN<8,4>(r, gC, s3);
#pragma unroll
    for (int k = 0; k < 8; ++k)
        psi[low | (((unsigned)k ^ s3) << J0) | high] = r[k];
}

// 3-bit pass over the 14-bit FULL state (r7 verbatim; two r[8] iterations).
template<int J0, int S3SH, int S3MSK>
__device__ __forceinline__ void pass3f(float2* psi, const float4* gc,
                                       unsigned t) {
    const float4 gA = gc[13 - (J0 + 0)];
    const float4 gB = gc[13 - (J0 + 1)];
    const float4 gC = gc[13 - (J0 + 2)];
    const unsigned s3 = (t >> S3SH) & (unsigned)S3MSK;
#pragma unroll
    for (int m = 0; m < 2; ++m) {
        const unsigned x    = t | ((unsigned)m << 10);   // 11 non-group bits
        const unsigned low  = x & ((1u << J0) - 1u);
        const unsigned high = (x >> J0) << (J0 + 3);
        float2 r[8];
#pragma unroll
        for (int k = 0; k < 8; ++k)
            r[k] = psi[low | (((unsigned)k ^ s3) << J0) | high];
        gateN<8,1>(r, gA, s3);
        gateN<8,2>(r, gB, s3);
        gateN<8,4>(r, gC, s3);
#pragma unroll
        for (int k = 0; k < 8; ++k)
            psi[low | (((unsigned)k ^ s3) << J0) | high] = r[k];
    }
}

// Full-state wires 1,0 + ring perm, cell 0 parked in spare LDS (r7 verbatim).
__device__ __forceinline__ void passE(float2* psi, float2* spare,
                                      const float4* gc4, int l, unsigned t) {
    const float4 g1 = gc4[l*NW + 1];   // index bit 12 -> wire 1
    const float4 g0 = gc4[l*NW + 0];   // index bit 13 -> wire 0

    unsigned v = t;
    v ^= v >> 1; v ^= v >> 2; v ^= v >> 4; v ^= v >> 8;
    const unsigned Rinv0 = (v & 0x0FFFu) | ((v & 1u) << 13);

    float2 c0[4];
#pragma unroll
    for (int k = 0; k < 4; ++k) c0[k] = psi[t | ((unsigned)k << 12)];
    gateN<4,1>(c0, g1, 0u);
    gateN<4,2>(c0, g0, 0u);
    spare[3*t+0] = c0[1];
    spare[3*t+1] = c0[2];
    spare[3*t+2] = c0[3];
    const float2 keep = c0[0];

    float2 r[12];
#pragma unroll
    for (int m = 1; m < 4; ++m) {
        const unsigned base = t | ((unsigned)m << 10);
#pragma unroll
        for (int k = 0; k < 4; ++k)
            r[(m-1)*4 + k] = psi[base | ((unsigned)k << 12)];
    }
#pragma unroll
    for (int m = 0; m < 3; ++m) {
        gateN<4,1>(r + 4*m, g1, 0u);
        gateN<4,2>(r + 4*m, g0, 0u);
    }

    __syncthreads();   // all psi gathers done -> in-place scatter is safe

#pragma unroll
    for (int m = 1; m < 4; ++m) {
        const unsigned Rb = Rinv0 ^ ((m & 1) ? 0x27FFu : 0u)
                                  ^ ((m & 2) ? 0x2FFFu : 0u);
#pragma unroll
        for (int k = 0; k < 4; ++k) {
            const unsigned CK = ((k & 1) ? B12_ : 0u) ^ ((k & 2) ? B13_ : 0u);
            psi[Rb ^ CK] = r[(m-1)*4 + k];
        }
    }
    psi[Rinv0]           = keep;
    psi[Rinv0 ^ B12_]    = spare[3*t+0];
    psi[Rinv0 ^ B13_]    = spare[3*t+1];
    psi[Rinv0 ^ 0x2000u] = spare[3*t+2];
}

// Half-state exit: wire-1 (bit12) gate + Rinv-relabel scatter (r9 verbatim).
__device__ __forceinline__ void exit_scatter(const float2* psi,
                                             float2* __restrict__ dst,
                                             float4 g1, unsigned q,
                                             unsigned tid) {
#pragma unroll
    for (int m = 0; m < 4; ++m) {
        const unsigned jc = tid + (unsigned)m * TPB;  // bits 0..11
        const float2 x0 = psi[jc];
        const float2 x1 = psi[jc | 0x1000u];
        float2 A0, A1;
        A0.x =  g1.x*x0.x - g1.y*x0.y + g1.z*x1.x - g1.w*x1.y;
        A0.y =  g1.x*x0.y + g1.y*x0.x + g1.z*x1.y + g1.w*x1.x;
        A1.x = -g1.z*x0.x - g1.w*x0.y + g1.x*x1.x + g1.y*x1.y;
        A1.y = -g1.z*x0.y + g1.w*x0.x + g1.x*x1.y - g1.y*x1.x;
        const unsigned d0 = sxmap(jc) ^ (q ? 0x1FFFu : 0u);
        dst[d0]           = A0;
        dst[d0 ^ 0x3FFFu] = A1;   // ^Rinv(e12)
    }
}

// D1: layer-0 product synth + layer-1 + exit -> SA (r9 verbatim, barriers
// between wave-local passes elided).
__global__ __launch_bounds__(TPB) void k_layer1(
    const float* __restrict__ states, const float* __restrict__ weights,
    float2* __restrict__ Sout)
{
    extern __shared__ float2 psi[];   // HALF float2 = 64 KB (84 KB requested)
    __shared__ float2 vfac[NW][2];
    __shared__ float2 T1[128];
    __shared__ float2 T2[128];
    __shared__ float4 gc[NW];
    const unsigned gid = blockIdx.x, q = gid >> 7, b = gid & 127u;
    const unsigned tid = threadIdx.x;

    if (tid < NW) {
        float4 g = fused_coef(weights, states, (int)b, 0, (int)tid);
        vfac[tid][0] = make_float2(g.x, g.y);
        vfac[tid][1] = make_float2(-g.z, g.w);
    }
    if (tid >= 64 && tid < 64 + NW)
        gc[tid - 64] = fused_coef(weights, states, (int)b, 1, (int)(tid - 64));
    __syncthreads();
    if (tid < 128) {
        float2 p = make_float2(1.0f, 0.0f);
#pragma unroll
        for (int j = 0; j < 7; ++j)
            p = cmul(p, vfac[13 - j][(tid >> j) & 1u]);
        T1[tid] = p;
    } else if (tid < 256) {
        const unsigned u = tid - 128;
        float2 p = make_float2(1.0f, 0.0f);
#pragma unroll
        for (int j = 7; j < 14; ++j)
            p = cmul(p, vfac[13 - j][(u >> (j - 7)) & 1u]);
        T2[u] = p;
    }
    __syncthreads();

#pragma unroll
    for (int m = 0; m < 8; ++m) {
        const unsigned I  = tid + (unsigned)m * TPB;
        const unsigned If = I | (q << 13);
        const unsigned lo  = (If ^ (If >> 1)) & 0x0FFFu;
        const unsigned y12 = ((If >> 12) ^ (If >> 13) ^ If) & 1u;
        const unsigned y13 = ((If >> 13) ^ If) & 1u;
        const unsigned J = lo | (y12 << 12) | (y13 << 13);
        psi[I] = cmul(T1[J & 127u], T2[J >> 7]);
    }
    __syncthreads();                       // synth is cross-wave

    pass3h<0, 1, 7>(psi, gc, tid);  WAVE_FENCE();   // exch: tid bits 0-2
    pass3h<3, 3, 1>(psi, gc, tid);  WAVE_FENCE();   // exch: tid bits 3-5
    pass3h<6, 0, 0>(psi, gc, tid);  __syncthreads(); // next exch: bits 6-8
    pass3h<9, 0, 0>(psi, gc, tid);  __syncthreads();

    exit_scatter(psi, Sout + (size_t)b * NSTATE, gc[1], q, tid);
}

// D2: full-state (one block per sample): deferred layer-1 wire-0 entry;
// layer 2 fully local (incl. ring perm); layer 3 local wires + final ring
// perm folded into the contraction masks; direct out[b] write.
__global__ __launch_bounds__(TPB) void k_rest(
    const float* __restrict__ states, const float* __restrict__ weights,
    const float* __restrict__ head_w, const float* __restrict__ head_b,
    const float2* __restrict__ Sin, float* __restrict__ out)
{
    extern __shared__ float2 dyn[];
    float2* psi   = dyn;            // 16384 float2 = 128 KB
    float2* spare = dyn + NSTATE;   //  3072 float2 =  24 KB
    __shared__ float4 gc4[NL * NW];
    __shared__ float wsum[TPB / 64];
    const unsigned b = blockIdx.x;
    const unsigned tid = threadIdx.x;

    if (tid < NL * NW)
        gc4[tid] = fused_coef(weights, states, (int)b,
                              (int)tid / NW, (int)tid % NW);
    __syncthreads();

    // Entry: r9-k_final's verified pair read (deferred layer-1 wire-0 gate).
    {
        const float4 ge = gc4[1 * NW + 0];
#pragma unroll
        for (int qm = 0; qm < 8; ++qm) {
            const unsigned q = (unsigned)qm >> 2;
            const unsigned m = (unsigned)qm & 3u;
            const float2* src = Sin + (size_t)b * NSTATE + (size_t)q * HALF;
            const unsigned ic = tid + m * TPB;            // bit12 = 0
            const float2 f0 = src[ic];
            const float2 f1 = src[ic ^ 0x1FFFu];
            const unsigned rc = (q ^ ic) & 1u;
            const float aar = ge.x, aai = rc ? -ge.y : ge.y;
            const float bbr = rc ? -ge.z : ge.z, bbi = ge.w;
            float2 oc, op;
            oc.x = aar*f0.x - aai*f0.y + bbr*f1.x - bbi*f1.y;
            oc.y = aar*f0.y + aai*f0.x + bbr*f1.y + bbi*f1.x;
            op.x = aar*f1.x + aai*f1.y - (bbr*f0.x + bbi*f0.y);
            op.y = aar*f1.y - aai*f1.x - (bbr*f0.y - bbi*f0.x);
            psi[(q << 13) | ic]            = oc;
            psi[(q << 13) | (ic ^ 0x1FFFu)] = op;
        }
    }
    __syncthreads();                       // entry is cross-wave

    // ---- layer 2: fully local ----
    pass3f<0, 1, 7>(psi, gc4 + 2 * NW, tid);  WAVE_FENCE();
    pass3f<3, 3, 1>(psi, gc4 + 2 * NW, tid);  WAVE_FENCE();
    pass3f<6, 0, 0>(psi, gc4 + 2 * NW, tid);  __syncthreads();
    pass3f<9, 0, 0>(psi, gc4 + 2 * NW, tid);  __syncthreads();
    passE(psi, spare, gc4, 2, tid);           __syncthreads();

    // ---- layer 3: local wires 13..2 ----
    pass3f<0, 1, 7>(psi, gc4 + 3 * NW, tid);  WAVE_FENCE();
    pass3f<3, 3, 1>(psi, gc4 + 3 * NW, tid);  WAVE_FENCE();
    pass3f<6, 0, 0>(psi, gc4 + 3 * NW, tid);  __syncthreads();
    pass3f<9, 0, 0>(psi, gc4 + 3 * NW, tid);  __syncthreads();

    // ---- layer-3 wires 1,0 + contraction with cv(Rinv(J)) (r11 verified) --
    float hw[NW];
#pragma unroll
    for (int i = 0; i < NW; ++i) hw[i] = head_w[i];
    float H = 0.0f, H12 = 0.0f;
#pragma unroll
    for (int i = 0; i < NW; ++i) H += hw[i];
#pragma unroll
    for (int i = 2; i < NW; ++i) H12 += hw[i];

    const float4 g1 = gc4[3 * NW + 1];   // wire 1 (bit12)
    const float4 g0 = gc4[3 * NW + 0];   // wire 0 (bit13)

    float acc = 0.0f;
#pragma unroll
    for (int m2 = 0; m2 < 4; ++m2) {
        const unsigned base = tid | ((unsigned)m2 << 10);  // bits 0..11
        float2 r[4];
#pragma unroll
        for (int k = 0; k < 4; ++k)
            r[k] = psi[base | ((unsigned)k << 12)];
        gateN<4,1>(r, g1, 0u);
        gateN<4,2>(r, g0, 0u);
        float A = 0.0f;
        unsigned sfx = 0u;
#pragma unroll
        for (int p = 11; p >= 0; --p) {
            sfx ^= (base >> p) & 1u;
            if (sfx) A += hw[13 - p];
        }
        const unsigned P = sfx;
#pragma unroll
        for (int k = 0; k < 4; ++k) {
            const unsigned u   = ((unsigned)k ^ ((unsigned)k >> 1)) & 1u; // J12^J13
            const unsigned b13 = P ^ ((unsigned)k & 1u);                  // parity J0..J12
            float sum = u ? (H12 - A) : A;
            if (u)   sum += hw[1];
            if (b13) sum += hw[0];
            const float cv = H - 2.0f * sum;
            acc += (r[k].x * r[k].x + r[k].y * r[k].y) * cv;
        }
    }
#pragma unroll
    for (int off = 32; off > 0; off >>= 1)
        acc += __shfl_down(acc, off, 64);
    if ((tid & 63u) == 0) wsum[tid >> 6] = acc;
    __syncthreads();
    if (tid == 0) {
        float tot = 0.0f;
#pragma unroll
        for (int i = 0; i < TPB / 64; ++i) tot += wsum[i];
        out[b] = tot + head_b[0];
    }
}

extern "C" void kernel_launch(void* const* d_in, const int* in_sizes, int n_in,
                              void* d_out, int out_size, void* d_ws, size_t ws_size,
                              hipStream_t stream) {
    const float* states  = (const float*)d_in[0];  // (128, 16384)
    const float* weights = (const float*)d_in[1];  // (4, 14, 2)
    const float* head_w  = (const float*)d_in[2];  // (1, 14)
    const float* head_b  = (const float*)d_in[3];  // (1,)
    float* out = (float*)d_out;                    // (128,)

    float2* SA = (float2*)d_ws;                    // 16 MB

    k_layer1<<<2 * BATCH, TPB, SHB1, stream>>>(states, weights, SA);
    k_rest  <<<BATCH, TPB, SHB2, stream>>>(states, weights, head_w, head_b,
                                           SA, out);
}